// Round 5
// baseline (790.918 us; speedup 1.0000x reference)
//
#include <hip/hip_runtime.h>

#define NNZC   1000000
#define NPOI   100000
#define NEDGE  50000
#define NUSER  50000
#define DIM    128
#define NL     3

#define PB     128         // chunks per matrix for hist/scatter passes
#define NBKT   196         // row-buckets per matrix (rows>>shift, shift 8 or 9 -> max bucket 195)
#define SCANN  (4 * NBKT * PB)   // 100352 counters (+1 sentinel)

static inline int ceil_div(int a, int b) { return (a + b - 1) / b; }

typedef unsigned int uint32;

// ---- bf16 helpers: rows stored as packed pairs (uint32 = 2 bf16, little-endian) ----
__device__ __forceinline__ float bfLO(uint32 u) { return __uint_as_float(u << 16); }
__device__ __forceinline__ float bfHI(uint32 u) { return __uint_as_float(u & 0xffff0000u); }
__device__ __forceinline__ uint32 bf16_rne(float f) {
    uint32 u = __float_as_uint(f);
    return (u + 0x7fffu + ((u >> 16) & 1u)) >> 16;
}
__device__ __forceinline__ uint32 bfPACK(float a, float b) {
    return bf16_rne(a) | (bf16_rne(b) << 16);
}
// ---- packed ELL entry: vals uniform [0,1) -> sign bit 0 -> 15-bit bf16; col fits 17 bits.
__device__ __forceinline__ uint32 csrPACK(int col, float val) {
    return ((uint32)col) | (bf16_rne(val) << 17);
}
__device__ __forceinline__ int   csrCOL(uint32 e) { return (int)(e & 0x1FFFFu); }
__device__ __forceinline__ float csrVAL(uint32 e) { return __uint_as_float((e >> 17) << 16); }

// per-matrix constants: tar(0), src(1), up(2), pu(3)
__device__ __constant__ const int c_nrows[4]  = { NEDGE, NPOI, NUSER, NPOI };
__device__ __constant__ const int c_cntoff[4] = { 0, NEDGE, NEDGE + NPOI, NEDGE + NPOI + NUSER };
__device__ __constant__ const int c_cap[4]    = { 64, 48, 64, 48 };
__device__ __constant__ const int c_shift[4]  = { 8, 9, 8, 9 };   // rows-per-bucket 256 / 512
__device__ __constant__ const long long c_elloff[4] = { 0, 3200000, 8000000, 11200000 };
// total ELL entries = 16,000,000 (64 MB)

// =============== ELL build: bucketed counting sort (4 passes, no global atomics) ===============

// Pass H: per-(matrix, chunk) histogram over row-buckets.  histG[(m*NBKT+b)*PB + p]
__global__ __launch_bounds__(1024) void histH_kernel(
    const int* __restrict__ r0, const int* __restrict__ r1,
    const int* __restrict__ r2, const int* __restrict__ r3,
    int* __restrict__ histG) {
    __shared__ int h[NBKT];
    int m = blockIdx.y, p = blockIdx.x;
    for (int i = threadIdx.x; i < NBKT; i += 1024) h[i] = 0;
    __syncthreads();
    const int* r = (m == 0) ? r0 : (m == 1) ? r1 : (m == 2) ? r2 : r3;
    int shift = c_shift[m];
    int lo = (int)(((long long)NNZC * p) >> 7);        // PB == 128
    int hi = (int)(((long long)NNZC * (p + 1)) >> 7);
    for (int i = lo + (int)threadIdx.x; i < hi; i += 1024)
        atomicAdd(&h[r[i] >> shift], 1);
    __syncthreads();
    for (int b = threadIdx.x; b < NBKT; b += 1024)
        histG[(m * NBKT + b) * PB + p] = h[b];
}

// Pass X: in-place exclusive scan of the 100352 counters (+ sentinel total at [SCANN]).
__global__ __launch_bounds__(256) void scan_kernel(int* __restrict__ g) {
    __shared__ int base[257];
    int t = threadIdx.x;
    const int chunk = SCANN / 256;   // 392
    int lo = t * chunk;
    int s = 0;
    for (int i = 0; i < chunk; i++) s += g[lo + i];
    base[t + 1] = s;
    __syncthreads();
    if (t == 0) {
        base[0] = 0;
        for (int i = 1; i <= 256; i++) base[i] += base[i - 1];
    }
    __syncthreads();
    int off = base[t];
    for (int i = 0; i < chunk; i++) { int v = g[lo + i]; g[lo + i] = off; off += v; }
    if (t == 255) g[SCANN] = base[256];
}

// Pass S: scatter (row, packed entry) records into exclusive dense ranges (bucket-major).
// PB=128 -> 512 blocks x 16 waves = 2 blocks/CU (round-4 ran 1 block/CU, 33% occupancy).
__global__ __launch_bounds__(1024) void scatS_kernel(
    const int* __restrict__ r0, const int* __restrict__ r1,
    const int* __restrict__ r2, const int* __restrict__ r3,
    const int* __restrict__ c0, const int* __restrict__ c1,
    const int* __restrict__ c2, const int* __restrict__ c3,
    const float* __restrict__ v0, const float* __restrict__ v1,
    const float* __restrict__ v2, const float* __restrict__ v3,
    const int* __restrict__ scanG, uint2* __restrict__ rec) {
    __shared__ int cur[NBKT];
    int m = blockIdx.y, p = blockIdx.x;
    for (int b = threadIdx.x; b < NBKT; b += 1024)
        cur[b] = scanG[(m * NBKT + b) * PB + p];
    __syncthreads();
    const int*   r = (m == 0) ? r0 : (m == 1) ? r1 : (m == 2) ? r2 : r3;
    const int*   c = (m == 0) ? c0 : (m == 1) ? c1 : (m == 2) ? c2 : c3;
    const float* v = (m == 0) ? v0 : (m == 1) ? v1 : (m == 2) ? v2 : v3;
    int shift = c_shift[m];
    int lo = (int)(((long long)NNZC * p) >> 7);
    int hi = (int)(((long long)NNZC * (p + 1)) >> 7);
    for (int i = lo + (int)threadIdx.x; i < hi; i += 1024) {
        int row = r[i];
        int pos = atomicAdd(&cur[row >> shift], 1);
        rec[pos] = make_uint2((uint32)row, csrPACK(c[i], v[i]));
    }
}

// Pass B: one block per (matrix, bucket).  Bucket rows are block-exclusive -> LDS row
// counters (no global atomics, no counts memset); ELL scatter confined to a 64-96 KB
// L2-resident region so lines fill before eviction.
__global__ __launch_bounds__(512) void fillB_kernel(
    const int* __restrict__ scanG, const uint2* __restrict__ rec,
    int* __restrict__ counts_all, uint32* __restrict__ ell) {
    __shared__ int cnt[512];
    int bx = (int)blockIdx.x;
    int m = bx / NBKT, b = bx - m * NBKT;
    int shift = c_shift[m];
    int rowlo = b << shift;
    int bklen = 1 << shift;
    for (int i = threadIdx.x; i < bklen; i += 512) cnt[i] = 0;
    __syncthreads();
    int lo = scanG[(m * NBKT + b) * PB];
    int hi = scanG[(m * NBKT + b + 1) * PB];   // b=195,m=3 -> scanG[SCANN] sentinel
    int cap = c_cap[m];
    uint32* ebase = ell + c_elloff[m];
    for (int i = lo + (int)threadIdx.x; i < hi; i += 512) {
        uint2 e = rec[i];
        int row = (int)e.x;
        int pos = atomicAdd(&cnt[row - rowlo], 1);
        ebase[(size_t)row * cap + pos] = e.y;
    }
    __syncthreads();
    int nrows_b = c_nrows[m] - rowlo;
    if (nrows_b > bklen) nrows_b = bklen;
    int* counts = counts_all + c_cntoff[m];
    for (int i = threadIdx.x; i < nrows_b; i += 512)
        counts[rowlo + i] = cnt[i];
}

// ---------------- softmax over the two 4-element attention vectors ----------------
__global__ void softmax4_kernel(const float* __restrict__ adi,
                                const float* __restrict__ amv,
                                float* __restrict__ w) {
    if (blockIdx.x == 0 && threadIdx.x == 0) {
        for (int b = 0; b < 2; b++) {
            const float* a = b ? amv : adi;
            float m = a[0];
            for (int l = 1; l < 4; l++) m = fmaxf(m, a[l]);
            float e[4]; float s = 0.f;
            for (int l = 0; l < 4; l++) { e[l] = __expf(a[l] - m); s += e[l]; }
            for (int l = 0; l < 4; l++) w[b * 4 + l] = e[l] / s;
        }
    }
}

// ---------------- fp32 -> packed bf16 cast (pois) ----------------
__global__ void cast_bf16_kernel(const float* __restrict__ src, uint32* __restrict__ dst, int npairs) {
    int i = blockIdx.x * blockDim.x + threadIdx.x;
    if (i < npairs) {
        float2 f = *(const float2*)(src + (size_t)i * 2);
        dst[i] = bfPACK(f.x, f.y);
    }
}

// ---- FMA on a broadcast (scalar) entry E and per-lane gathered word U ----
#define GPROC(E, U) do { float _v = csrVAL(E); \
    acc.x = fmaf(_v, bfLO(U), acc.x); acc.y = fmaf(_v, bfHI(U), acc.y); } while (0)

// ---------------- hop1 SpMM: y_bf[row] = A @ x_bf, one wave/row, ELL ----------------
// ELL row data is wave-uniform: readfirstlane(row) makes the row pointer an SGPR so
// entry loads become s_load (scalar cache), col/val extraction runs on the scalar pipe,
// and the 64 ds_bpermute broadcasts per row disappear.  Inner loop per entry:
// 1 global_load_dword (saddr+lane*4) + 2 bf16 unpack + 2 FMA.
template<int CAP>
__global__ __launch_bounds__(256) void spmm1_kernel(
    const int* __restrict__ counts, const uint32* __restrict__ ell,
    const uint32* __restrict__ xbf, uint32* __restrict__ ybf, int n_rows) {
    int row = (int)((blockIdx.x * blockDim.x + threadIdx.x) >> 6);
    int lane = (int)(threadIdx.x & 63);
    if (row >= n_rows) return;
    row = __builtin_amdgcn_readfirstlane(row);
    int cnt = __builtin_amdgcn_readfirstlane(counts[row]);
    const uint32* erow = ell + row * CAP;
    const uint4*  erow4 = (const uint4*)erow;   // row*CAP*4 is 16B-aligned for CAP 48/64
    float2 acc = make_float2(0.f, 0.f);
    int j = 0;
    for (; j + 8 <= cnt; j += 8) {
        uint4 qa = erow4[j >> 2], qb = erow4[(j >> 2) + 1];
        uint32 u0 = xbf[csrCOL(qa.x) * 64 + lane];
        uint32 u1 = xbf[csrCOL(qa.y) * 64 + lane];
        uint32 u2 = xbf[csrCOL(qa.z) * 64 + lane];
        uint32 u3 = xbf[csrCOL(qa.w) * 64 + lane];
        uint32 u4 = xbf[csrCOL(qb.x) * 64 + lane];
        uint32 u5 = xbf[csrCOL(qb.y) * 64 + lane];
        uint32 u6 = xbf[csrCOL(qb.z) * 64 + lane];
        uint32 u7 = xbf[csrCOL(qb.w) * 64 + lane];
        GPROC(qa.x, u0); GPROC(qa.y, u1); GPROC(qa.z, u2); GPROC(qa.w, u3);
        GPROC(qb.x, u4); GPROC(qb.y, u5); GPROC(qb.z, u6); GPROC(qb.w, u7);
    }
    for (; j + 4 <= cnt; j += 4) {
        uint4 q = erow4[j >> 2];
        uint32 u0 = xbf[csrCOL(q.x) * 64 + lane];
        uint32 u1 = xbf[csrCOL(q.y) * 64 + lane];
        uint32 u2 = xbf[csrCOL(q.z) * 64 + lane];
        uint32 u3 = xbf[csrCOL(q.w) * 64 + lane];
        GPROC(q.x, u0); GPROC(q.y, u1); GPROC(q.z, u2); GPROC(q.w, u3);
    }
    for (; j < cnt; j++) {
        uint32 e = erow[j];
        uint32 u = xbf[csrCOL(e) * 64 + lane];
        GPROC(e, u);
    }
    ybf[row * 64 + lane] = bfPACK(acc.x, acc.y);
}

// ---------------- hop2: xnew = relu(A@m)+xin, bf16 in/out, ELL ----------------
template<int CAP>
__global__ __launch_bounds__(256) void spmm2_kernel(
    const int* __restrict__ counts, const uint32* __restrict__ ell,
    const uint32* __restrict__ mbf, const uint32* __restrict__ xinbf,
    uint32* __restrict__ xoutbf, int n_rows) {
    int row = (int)((blockIdx.x * blockDim.x + threadIdx.x) >> 6);
    int lane = (int)(threadIdx.x & 63);
    if (row >= n_rows) return;
    row = __builtin_amdgcn_readfirstlane(row);
    int cnt = __builtin_amdgcn_readfirstlane(counts[row]);
    const uint32* erow = ell + row * CAP;
    const uint4*  erow4 = (const uint4*)erow;
    float2 acc = make_float2(0.f, 0.f);
    int j = 0;
    for (; j + 8 <= cnt; j += 8) {
        uint4 qa = erow4[j >> 2], qb = erow4[(j >> 2) + 1];
        uint32 u0 = mbf[csrCOL(qa.x) * 64 + lane];
        uint32 u1 = mbf[csrCOL(qa.y) * 64 + lane];
        uint32 u2 = mbf[csrCOL(qa.z) * 64 + lane];
        uint32 u3 = mbf[csrCOL(qa.w) * 64 + lane];
        uint32 u4 = mbf[csrCOL(qb.x) * 64 + lane];
        uint32 u5 = mbf[csrCOL(qb.y) * 64 + lane];
        uint32 u6 = mbf[csrCOL(qb.z) * 64 + lane];
        uint32 u7 = mbf[csrCOL(qb.w) * 64 + lane];
        GPROC(qa.x, u0); GPROC(qa.y, u1); GPROC(qa.z, u2); GPROC(qa.w, u3);
        GPROC(qb.x, u4); GPROC(qb.y, u5); GPROC(qb.z, u6); GPROC(qb.w, u7);
    }
    for (; j + 4 <= cnt; j += 4) {
        uint4 q = erow4[j >> 2];
        uint32 u0 = mbf[csrCOL(q.x) * 64 + lane];
        uint32 u1 = mbf[csrCOL(q.y) * 64 + lane];
        uint32 u2 = mbf[csrCOL(q.z) * 64 + lane];
        uint32 u3 = mbf[csrCOL(q.w) * 64 + lane];
        GPROC(q.x, u0); GPROC(q.y, u1); GPROC(q.z, u2); GPROC(q.w, u3);
    }
    for (; j < cnt; j++) {
        uint32 e = erow[j];
        uint32 u = mbf[csrCOL(e) * 64 + lane];
        GPROC(e, u);
    }
    int o32 = row * 64 + lane;
    uint32 ui = xinbf[o32];
    float xn0 = fmaxf(acc.x, 0.f) + bfLO(ui);
    float xn1 = fmaxf(acc.y, 0.f) + bfHI(ui);
    xoutbf[o32] = bfPACK(xn0, xn1);
}

// ---------------- epilogues: out = (w0di+w0mv)*pois + sum_l w_l * x_l ----------------
__global__ void epi1_kernel(const float* __restrict__ pois,
                            const uint32* __restrict__ x1, const uint32* __restrict__ x2,
                            const uint32* __restrict__ x3, const float* __restrict__ w,
                            float* __restrict__ out) {
    int i = blockIdx.x * blockDim.x + threadIdx.x;
    if (i < NPOI * 64) {
        float w0 = w[0] + w[4];
        float2 pf = ((const float2*)pois)[i];
        uint32 u1 = x1[i], u2 = x2[i], u3 = x3[i];
        float o0 = w0 * pf.x + w[1] * bfLO(u1) + w[2] * bfLO(u2) + w[3] * bfLO(u3);
        float o1 = w0 * pf.y + w[1] * bfHI(u1) + w[2] * bfHI(u2) + w[3] * bfHI(u3);
        ((float2*)out)[i] = make_float2(o0, o1);
    }
}

__global__ void epi2_kernel(const uint32* __restrict__ x1, const uint32* __restrict__ x2,
                            const uint32* __restrict__ x3, const float* __restrict__ w,
                            float* __restrict__ out) {
    int i = blockIdx.x * blockDim.x + threadIdx.x;
    if (i < NPOI * 64) {
        uint32 u1 = x1[i], u2 = x2[i], u3 = x3[i];
        float2 ov = ((float2*)out)[i];
        ov.x += w[5] * bfLO(u1) + w[6] * bfLO(u2) + w[7] * bfLO(u3);
        ov.y += w[5] * bfHI(u1) + w[6] * bfHI(u2) + w[7] * bfHI(u3);
        ((float2*)out)[i] = ov;
    }
}

extern "C" void kernel_launch(void* const* d_in, const int* in_sizes, int n_in,
                              void* d_out, int out_size, void* d_ws, size_t ws_size,
                              hipStream_t stream) {
    const float* pois = (const float*)d_in[0];
    const int*   rows_in[4] = { (const int*)d_in[1], (const int*)d_in[4],
                                (const int*)d_in[7], (const int*)d_in[10] };
    const int*   cols_in[4] = { (const int*)d_in[2], (const int*)d_in[5],
                                (const int*)d_in[8], (const int*)d_in[11] };
    const float* vals_in[4] = { (const float*)d_in[3], (const float*)d_in[6],
                                (const float*)d_in[9], (const float*)d_in[12] };
    const float* attn_di = (const float*)d_in[13];
    const float* attn_mv = (const float*)d_in[14];
    float* out = (float*)d_out;

    const int NTOT = NEDGE + NPOI + NUSER + NPOI;  // 300000
    const int cnt_off[4] = { 0, NEDGE, NEDGE + NPOI, NEDGE + NPOI + NUSER };
    const long long ell_off[4] = { 0, 3200000, 8000000, 11200000 };

    // -------- workspace carve-up (~182 MB) --------
    char* p = (char*)d_ws;
    float*  wsoft      = (float*)p;  p += 256;
    int*    counts_all = (int*)p;    p += (size_t)NTOT * 4;
    p = (char*)(((size_t)p + 255) & ~255ull);
    int*    scanG      = (int*)p;    p += (size_t)(SCANN + 64) * 4;  // 100353 + pad
    p = (char*)(((size_t)p + 255) & ~255ull);
    uint32* ell        = (uint32*)p; p += (size_t)16000000 * 4;     // 64 MB ELL
    uint32* mbf        = (uint32*)p; p += (size_t)NEDGE * 64 * 4;   // 12.8 MB
    uint32* poisbf     = (uint32*)p; p += (size_t)NPOI * 64 * 4;    // 25.6 MB
    uint32* xl[3];
    for (int l = 0; l < 3; l++) { xl[l] = (uint32*)p; p += (size_t)NPOI * 64 * 4; }
    // records (32 MB) alias xl[0..1] (51.2 MB): consumed by fillB before spmm writes xl.
    uint2* rec = (uint2*)xl[0];
    (void)ws_size; (void)out_size; (void)n_in; (void)in_sizes;

    // -------- ELL build: hist -> scan -> scatter-sort -> bucket fill --------
    histH_kernel<<<dim3(PB, 4), 1024, 0, stream>>>(
        rows_in[0], rows_in[1], rows_in[2], rows_in[3], scanG);
    scan_kernel<<<1, 256, 0, stream>>>(scanG);
    scatS_kernel<<<dim3(PB, 4), 1024, 0, stream>>>(
        rows_in[0], rows_in[1], rows_in[2], rows_in[3],
        cols_in[0], cols_in[1], cols_in[2], cols_in[3],
        vals_in[0], vals_in[1], vals_in[2], vals_in[3],
        scanG, rec);
    fillB_kernel<<<4 * NBKT, 512, 0, stream>>>(scanG, rec, counts_all, ell);

    // -------- attention weights + bf16 cast of pois --------
    softmax4_kernel<<<1, 64, 0, stream>>>(attn_di, attn_mv, wsoft);
    cast_bf16_kernel<<<ceil_div(NPOI * 64, 256), 256, 0, stream>>>(pois, poisbf, NPOI * 64);

    // -------- two branches, 3 layers each; epilogue per branch --------
    for (int br = 0; br < 2; br++) {
        int m1i = br ? 2 : 0;   // up  : tar   (50k rows, CAP 64)
        int m2i = br ? 3 : 1;   // pu  : src   (100k rows, CAP 48)
        const int* cn1 = counts_all + cnt_off[m1i];
        const int* cn2 = counts_all + cnt_off[m2i];
        const uint32* el1 = ell + ell_off[m1i];
        const uint32* el2 = ell + ell_off[m2i];
        const int n1 = 50000;  // NEDGE == NUSER
        const uint32* xcur = poisbf;
        for (int l = 1; l <= NL; l++) {
            spmm1_kernel<64><<<ceil_div(n1, 4), 256, 0, stream>>>(cn1, el1, xcur, mbf, n1);
            spmm2_kernel<48><<<ceil_div(NPOI, 4), 256, 0, stream>>>(
                cn2, el2, mbf, xcur, xl[l - 1], NPOI);
            xcur = xl[l - 1];
        }
        if (br == 0)
            epi1_kernel<<<ceil_div(NPOI * 64, 256), 256, 0, stream>>>(
                pois, xl[0], xl[1], xl[2], wsoft, out);
        else
            epi2_kernel<<<ceil_div(NPOI * 64, 256), 256, 0, stream>>>(
                xl[0], xl[1], xl[2], wsoft, out);
    }
}

// Round 6
// 777.972 us; speedup vs baseline: 1.0166x; 1.0166x over previous
//
#include <hip/hip_runtime.h>

#define NNZC   1000000
#define NPOI   100000
#define NEDGE  50000
#define NUSER  50000
#define DIM    128
#define NL     3

#define PB     64          // chunks per matrix (PB=128 regressed: 320B runs re-amplified writes)
#define NBKT   196         // row-buckets per matrix (rows>>shift, shift 8 or 9 -> max bucket 195)
#define SCANN  (4 * NBKT * PB)   // 50176 counters (+1 sentinel)

static inline int ceil_div(int a, int b) { return (a + b - 1) / b; }

typedef unsigned int uint32;

// ---- bf16 helpers: rows stored as packed pairs (uint32 = 2 bf16, little-endian) ----
__device__ __forceinline__ float bfLO(uint32 u) { return __uint_as_float(u << 16); }
__device__ __forceinline__ float bfHI(uint32 u) { return __uint_as_float(u & 0xffff0000u); }
__device__ __forceinline__ uint32 bf16_rne(float f) {
    uint32 u = __float_as_uint(f);
    return (u + 0x7fffu + ((u >> 16) & 1u)) >> 16;
}
__device__ __forceinline__ uint32 bfPACK(float a, float b) {
    return bf16_rne(a) | (bf16_rne(b) << 16);
}
// ---- packed ELL entry: vals uniform [0,1) -> sign bit 0 -> 15-bit bf16; col fits 17 bits.
__device__ __forceinline__ uint32 csrPACK(int col, float val) {
    return ((uint32)col) | (bf16_rne(val) << 17);
}
__device__ __forceinline__ int   csrCOL(uint32 e) { return (int)(e & 0x1FFFFu); }
__device__ __forceinline__ float csrVAL(uint32 e) { return __uint_as_float((e >> 17) << 16); }

// per-matrix constants: tar(0), src(1), up(2), pu(3)
__device__ __constant__ const int c_nrows[4]  = { NEDGE, NPOI, NUSER, NPOI };
__device__ __constant__ const int c_cntoff[4] = { 0, NEDGE, NEDGE + NPOI, NEDGE + NPOI + NUSER };
__device__ __constant__ const int c_cap[4]    = { 64, 48, 64, 48 };
__device__ __constant__ const int c_shift[4]  = { 8, 9, 8, 9 };   // rows-per-bucket 256 / 512
__device__ __constant__ const long long c_elloff[4] = { 0, 3200000, 8000000, 11200000 };
// total ELL entries = 16,000,000 (64 MB)

// =============== ELL build: bucketed counting sort (4 passes, no global atomics) ===============

// Pass H: per-(matrix, chunk) histogram over row-buckets.  histG[(m*NBKT+b)*PB + p]
__global__ __launch_bounds__(1024) void histH_kernel(
    const int* __restrict__ r0, const int* __restrict__ r1,
    const int* __restrict__ r2, const int* __restrict__ r3,
    int* __restrict__ histG) {
    __shared__ int h[NBKT];
    int m = blockIdx.y, p = blockIdx.x;
    for (int i = threadIdx.x; i < NBKT; i += 1024) h[i] = 0;
    __syncthreads();
    const int* r = (m == 0) ? r0 : (m == 1) ? r1 : (m == 2) ? r2 : r3;
    int shift = c_shift[m];
    int lo = (int)(((long long)NNZC * p) >> 6);        // PB == 64
    int hi = (int)(((long long)NNZC * (p + 1)) >> 6);
    for (int i = lo + (int)threadIdx.x; i < hi; i += 1024)
        atomicAdd(&h[r[i] >> shift], 1);
    __syncthreads();
    for (int b = threadIdx.x; b < NBKT; b += 1024)
        histG[(m * NBKT + b) * PB + p] = h[b];
}

// Pass X: in-place exclusive scan of the 50176 counters (+ sentinel total at [SCANN]).
__global__ __launch_bounds__(256) void scan_kernel(int* __restrict__ g) {
    __shared__ int base[257];
    int t = threadIdx.x;
    const int chunk = SCANN / 256;   // 196
    int lo = t * chunk;
    int s = 0;
    for (int i = 0; i < chunk; i++) s += g[lo + i];
    base[t + 1] = s;
    __syncthreads();
    if (t == 0) {
        base[0] = 0;
        for (int i = 1; i <= 256; i++) base[i] += base[i - 1];
    }
    __syncthreads();
    int off = base[t];
    for (int i = 0; i < chunk; i++) { int v = g[lo + i]; g[lo + i] = off; off += v; }
    if (t == 255) g[SCANN] = base[256];
}

// Pass S: scatter (row, packed entry) records into exclusive dense ranges (bucket-major).
// PB=64: ~640B contiguous runs (PB=128's 320B runs doubled partial-line write-amp).
__global__ __launch_bounds__(1024) void scatS_kernel(
    const int* __restrict__ r0, const int* __restrict__ r1,
    const int* __restrict__ r2, const int* __restrict__ r3,
    const int* __restrict__ c0, const int* __restrict__ c1,
    const int* __restrict__ c2, const int* __restrict__ c3,
    const float* __restrict__ v0, const float* __restrict__ v1,
    const float* __restrict__ v2, const float* __restrict__ v3,
    const int* __restrict__ scanG, uint2* __restrict__ rec) {
    __shared__ int cur[NBKT];
    int m = blockIdx.y, p = blockIdx.x;
    for (int b = threadIdx.x; b < NBKT; b += 1024)
        cur[b] = scanG[(m * NBKT + b) * PB + p];
    __syncthreads();
    const int*   r = (m == 0) ? r0 : (m == 1) ? r1 : (m == 2) ? r2 : r3;
    const int*   c = (m == 0) ? c0 : (m == 1) ? c1 : (m == 2) ? c2 : c3;
    const float* v = (m == 0) ? v0 : (m == 1) ? v1 : (m == 2) ? v2 : v3;
    int shift = c_shift[m];
    int lo = (int)(((long long)NNZC * p) >> 6);
    int hi = (int)(((long long)NNZC * (p + 1)) >> 6);
    for (int i = lo + (int)threadIdx.x; i < hi; i += 1024) {
        int row = r[i];
        int pos = atomicAdd(&cur[row >> shift], 1);
        rec[pos] = make_uint2((uint32)row, csrPACK(c[i], v[i]));
    }
}

// Pass B: one block per (matrix, bucket).  Bucket rows are block-exclusive -> LDS row
// counters (no global atomics, no counts memset); ELL scatter confined to a 64-96 KB
// L2-resident region so lines fill before eviction.
__global__ __launch_bounds__(512) void fillB_kernel(
    const int* __restrict__ scanG, const uint2* __restrict__ rec,
    int* __restrict__ counts_all, uint32* __restrict__ ell) {
    __shared__ int cnt[512];
    int bx = (int)blockIdx.x;
    int m = bx / NBKT, b = bx - m * NBKT;
    int shift = c_shift[m];
    int rowlo = b << shift;
    int bklen = 1 << shift;
    for (int i = threadIdx.x; i < bklen; i += 512) cnt[i] = 0;
    __syncthreads();
    int lo = scanG[(m * NBKT + b) * PB];
    int hi = scanG[(m * NBKT + b + 1) * PB];   // b=195,m=3 -> scanG[SCANN] sentinel
    int cap = c_cap[m];
    uint32* ebase = ell + c_elloff[m];
    for (int i = lo + (int)threadIdx.x; i < hi; i += 512) {
        uint2 e = rec[i];
        int row = (int)e.x;
        int pos = atomicAdd(&cnt[row - rowlo], 1);
        ebase[(size_t)row * cap + pos] = e.y;
    }
    __syncthreads();
    int nrows_b = c_nrows[m] - rowlo;
    if (nrows_b > bklen) nrows_b = bklen;
    int* counts = counts_all + c_cntoff[m];
    for (int i = threadIdx.x; i < nrows_b; i += 512)
        counts[rowlo + i] = cnt[i];
}

// ---------------- softmax over the two 4-element attention vectors ----------------
__global__ void softmax4_kernel(const float* __restrict__ adi,
                                const float* __restrict__ amv,
                                float* __restrict__ w) {
    if (blockIdx.x == 0 && threadIdx.x == 0) {
        for (int b = 0; b < 2; b++) {
            const float* a = b ? amv : adi;
            float m = a[0];
            for (int l = 1; l < 4; l++) m = fmaxf(m, a[l]);
            float e[4]; float s = 0.f;
            for (int l = 0; l < 4; l++) { e[l] = __expf(a[l] - m); s += e[l]; }
            for (int l = 0; l < 4; l++) w[b * 4 + l] = e[l] / s;
        }
    }
}

// ---------------- fp32 -> packed bf16 cast (pois) ----------------
__global__ void cast_bf16_kernel(const float* __restrict__ src, uint32* __restrict__ dst, int npairs) {
    int i = blockIdx.x * blockDim.x + threadIdx.x;
    if (i < npairs) {
        float2 f = *(const float2*)(src + (size_t)i * 2);
        dst[i] = bfPACK(f.x, f.y);
    }
}

// ---- 8-FMA helper: one scalar entry value v against a 16B (8 bf16) operand slice ----
__device__ __forceinline__ void fma8(float2& a0, float2& a1, float2& a2, float2& a3,
                                     float v, uint4 u) {
    a0.x = fmaf(v, bfLO(u.x), a0.x); a0.y = fmaf(v, bfHI(u.x), a0.y);
    a1.x = fmaf(v, bfLO(u.y), a1.x); a1.y = fmaf(v, bfHI(u.y), a1.y);
    a2.x = fmaf(v, bfLO(u.z), a2.x); a2.y = fmaf(v, bfHI(u.z), a2.y);
    a3.x = fmaf(v, bfLO(u.w), a3.x); a3.y = fmaf(v, bfHI(u.w), a3.y);
}

// ---------------- hop1 SpMM: y_bf[row] = A @ x_bf ----------------
// 16-lane group per row: lane t gathers uint4 (16B = 8 bf16) of the 256B operand row.
// A wave carries 4 independent rows -> each gather instruction moves 1KB (4x the old
// 64-lane/row layout) and unroll-8 keeps ~8KB in flight per wave.  cnt divergence
// across the 4 groups is exec-masked (adjacent Poisson rows, ~15% overhead).
template<int CAP>
__global__ __launch_bounds__(256) void spmm1_kernel(
    const int* __restrict__ counts, const uint32* __restrict__ ell,
    const uint32* __restrict__ xbf, uint32* __restrict__ ybf, int n_rows) {
    int row = (int)((blockIdx.x * blockDim.x + threadIdx.x) >> 4);
    int t   = (int)(threadIdx.x & 15);
    if (row >= n_rows) return;
    int cnt = counts[row];
    const uint32* erow = ell + (size_t)row * CAP;
    float2 a0 = {0.f,0.f}, a1 = {0.f,0.f}, a2 = {0.f,0.f}, a3 = {0.f,0.f};
    int j = 0;
    for (; j + 8 <= cnt; j += 8) {
        uint4 qa = *(const uint4*)(erow + j);
        uint4 qb = *(const uint4*)(erow + j + 4);
        uint4 u0 = *((const uint4*)(xbf + (size_t)csrCOL(qa.x) * 64) + t);
        uint4 u1 = *((const uint4*)(xbf + (size_t)csrCOL(qa.y) * 64) + t);
        uint4 u2 = *((const uint4*)(xbf + (size_t)csrCOL(qa.z) * 64) + t);
        uint4 u3 = *((const uint4*)(xbf + (size_t)csrCOL(qa.w) * 64) + t);
        uint4 u4 = *((const uint4*)(xbf + (size_t)csrCOL(qb.x) * 64) + t);
        uint4 u5 = *((const uint4*)(xbf + (size_t)csrCOL(qb.y) * 64) + t);
        uint4 u6 = *((const uint4*)(xbf + (size_t)csrCOL(qb.z) * 64) + t);
        uint4 u7 = *((const uint4*)(xbf + (size_t)csrCOL(qb.w) * 64) + t);
        fma8(a0,a1,a2,a3, csrVAL(qa.x), u0); fma8(a0,a1,a2,a3, csrVAL(qa.y), u1);
        fma8(a0,a1,a2,a3, csrVAL(qa.z), u2); fma8(a0,a1,a2,a3, csrVAL(qa.w), u3);
        fma8(a0,a1,a2,a3, csrVAL(qb.x), u4); fma8(a0,a1,a2,a3, csrVAL(qb.y), u5);
        fma8(a0,a1,a2,a3, csrVAL(qb.z), u6); fma8(a0,a1,a2,a3, csrVAL(qb.w), u7);
    }
    for (; j + 4 <= cnt; j += 4) {
        uint4 q = *(const uint4*)(erow + j);
        uint4 u0 = *((const uint4*)(xbf + (size_t)csrCOL(q.x) * 64) + t);
        uint4 u1 = *((const uint4*)(xbf + (size_t)csrCOL(q.y) * 64) + t);
        uint4 u2 = *((const uint4*)(xbf + (size_t)csrCOL(q.z) * 64) + t);
        uint4 u3 = *((const uint4*)(xbf + (size_t)csrCOL(q.w) * 64) + t);
        fma8(a0,a1,a2,a3, csrVAL(q.x), u0); fma8(a0,a1,a2,a3, csrVAL(q.y), u1);
        fma8(a0,a1,a2,a3, csrVAL(q.z), u2); fma8(a0,a1,a2,a3, csrVAL(q.w), u3);
    }
    for (; j < cnt; j++) {
        uint32 e = erow[j];
        uint4 u = *((const uint4*)(xbf + (size_t)csrCOL(e) * 64) + t);
        fma8(a0,a1,a2,a3, csrVAL(e), u);
    }
    uint4 o;
    o.x = bfPACK(a0.x, a0.y); o.y = bfPACK(a1.x, a1.y);
    o.z = bfPACK(a2.x, a2.y); o.w = bfPACK(a3.x, a3.y);
    *((uint4*)(ybf + (size_t)row * 64) + t) = o;
}

// ---------------- hop2: xnew = relu(A@m)+xin, bf16 in/out, ELL ----------------
template<int CAP>
__global__ __launch_bounds__(256) void spmm2_kernel(
    const int* __restrict__ counts, const uint32* __restrict__ ell,
    const uint32* __restrict__ mbf, const uint32* __restrict__ xinbf,
    uint32* __restrict__ xoutbf, int n_rows) {
    int row = (int)((blockIdx.x * blockDim.x + threadIdx.x) >> 4);
    int t   = (int)(threadIdx.x & 15);
    if (row >= n_rows) return;
    int cnt = counts[row];
    const uint32* erow = ell + (size_t)row * CAP;
    float2 a0 = {0.f,0.f}, a1 = {0.f,0.f}, a2 = {0.f,0.f}, a3 = {0.f,0.f};
    int j = 0;
    for (; j + 8 <= cnt; j += 8) {
        uint4 qa = *(const uint4*)(erow + j);
        uint4 qb = *(const uint4*)(erow + j + 4);
        uint4 u0 = *((const uint4*)(mbf + (size_t)csrCOL(qa.x) * 64) + t);
        uint4 u1 = *((const uint4*)(mbf + (size_t)csrCOL(qa.y) * 64) + t);
        uint4 u2 = *((const uint4*)(mbf + (size_t)csrCOL(qa.z) * 64) + t);
        uint4 u3 = *((const uint4*)(mbf + (size_t)csrCOL(qa.w) * 64) + t);
        uint4 u4 = *((const uint4*)(mbf + (size_t)csrCOL(qb.x) * 64) + t);
        uint4 u5 = *((const uint4*)(mbf + (size_t)csrCOL(qb.y) * 64) + t);
        uint4 u6 = *((const uint4*)(mbf + (size_t)csrCOL(qb.z) * 64) + t);
        uint4 u7 = *((const uint4*)(mbf + (size_t)csrCOL(qb.w) * 64) + t);
        fma8(a0,a1,a2,a3, csrVAL(qa.x), u0); fma8(a0,a1,a2,a3, csrVAL(qa.y), u1);
        fma8(a0,a1,a2,a3, csrVAL(qa.z), u2); fma8(a0,a1,a2,a3, csrVAL(qa.w), u3);
        fma8(a0,a1,a2,a3, csrVAL(qb.x), u4); fma8(a0,a1,a2,a3, csrVAL(qb.y), u5);
        fma8(a0,a1,a2,a3, csrVAL(qb.z), u6); fma8(a0,a1,a2,a3, csrVAL(qb.w), u7);
    }
    for (; j + 4 <= cnt; j += 4) {
        uint4 q = *(const uint4*)(erow + j);
        uint4 u0 = *((const uint4*)(mbf + (size_t)csrCOL(q.x) * 64) + t);
        uint4 u1 = *((const uint4*)(mbf + (size_t)csrCOL(q.y) * 64) + t);
        uint4 u2 = *((const uint4*)(mbf + (size_t)csrCOL(q.z) * 64) + t);
        uint4 u3 = *((const uint4*)(mbf + (size_t)csrCOL(q.w) * 64) + t);
        fma8(a0,a1,a2,a3, csrVAL(q.x), u0); fma8(a0,a1,a2,a3, csrVAL(q.y), u1);
        fma8(a0,a1,a2,a3, csrVAL(q.z), u2); fma8(a0,a1,a2,a3, csrVAL(q.w), u3);
    }
    for (; j < cnt; j++) {
        uint32 e = erow[j];
        uint4 u = *((const uint4*)(mbf + (size_t)csrCOL(e) * 64) + t);
        fma8(a0,a1,a2,a3, csrVAL(e), u);
    }
    uint4 ui = *((const uint4*)(xinbf + (size_t)row * 64) + t);
    uint4 o;
    o.x = bfPACK(fmaxf(a0.x, 0.f) + bfLO(ui.x), fmaxf(a0.y, 0.f) + bfHI(ui.x));
    o.y = bfPACK(fmaxf(a1.x, 0.f) + bfLO(ui.y), fmaxf(a1.y, 0.f) + bfHI(ui.y));
    o.z = bfPACK(fmaxf(a2.x, 0.f) + bfLO(ui.z), fmaxf(a2.y, 0.f) + bfHI(ui.z));
    o.w = bfPACK(fmaxf(a3.x, 0.f) + bfLO(ui.w), fmaxf(a3.y, 0.f) + bfHI(ui.w));
    *((uint4*)(xoutbf + (size_t)row * 64) + t) = o;
}

// ---------------- epilogues: out = (w0di+w0mv)*pois + sum_l w_l * x_l ----------------
__global__ void epi1_kernel(const float* __restrict__ pois,
                            const uint32* __restrict__ x1, const uint32* __restrict__ x2,
                            const uint32* __restrict__ x3, const float* __restrict__ w,
                            float* __restrict__ out) {
    int i = blockIdx.x * blockDim.x + threadIdx.x;
    if (i < NPOI * 64) {
        float w0 = w[0] + w[4];
        float2 pf = ((const float2*)pois)[i];
        uint32 u1 = x1[i], u2 = x2[i], u3 = x3[i];
        float o0 = w0 * pf.x + w[1] * bfLO(u1) + w[2] * bfLO(u2) + w[3] * bfLO(u3);
        float o1 = w0 * pf.y + w[1] * bfHI(u1) + w[2] * bfHI(u2) + w[3] * bfHI(u3);
        ((float2*)out)[i] = make_float2(o0, o1);
    }
}

__global__ void epi2_kernel(const uint32* __restrict__ x1, const uint32* __restrict__ x2,
                            const uint32* __restrict__ x3, const float* __restrict__ w,
                            float* __restrict__ out) {
    int i = blockIdx.x * blockDim.x + threadIdx.x;
    if (i < NPOI * 64) {
        uint32 u1 = x1[i], u2 = x2[i], u3 = x3[i];
        float2 ov = ((float2*)out)[i];
        ov.x += w[5] * bfLO(u1) + w[6] * bfLO(u2) + w[7] * bfLO(u3);
        ov.y += w[5] * bfHI(u1) + w[6] * bfHI(u2) + w[7] * bfHI(u3);
        ((float2*)out)[i] = ov;
    }
}

extern "C" void kernel_launch(void* const* d_in, const int* in_sizes, int n_in,
                              void* d_out, int out_size, void* d_ws, size_t ws_size,
                              hipStream_t stream) {
    const float* pois = (const float*)d_in[0];
    const int*   rows_in[4] = { (const int*)d_in[1], (const int*)d_in[4],
                                (const int*)d_in[7], (const int*)d_in[10] };
    const int*   cols_in[4] = { (const int*)d_in[2], (const int*)d_in[5],
                                (const int*)d_in[8], (const int*)d_in[11] };
    const float* vals_in[4] = { (const float*)d_in[3], (const float*)d_in[6],
                                (const float*)d_in[9], (const float*)d_in[12] };
    const float* attn_di = (const float*)d_in[13];
    const float* attn_mv = (const float*)d_in[14];
    float* out = (float*)d_out;

    const int NTOT = NEDGE + NPOI + NUSER + NPOI;  // 300000
    const int cnt_off[4] = { 0, NEDGE, NEDGE + NPOI, NEDGE + NPOI + NUSER };
    const long long ell_off[4] = { 0, 3200000, 8000000, 11200000 };

    // -------- workspace carve-up (~182 MB) --------
    char* p = (char*)d_ws;
    float*  wsoft      = (float*)p;  p += 256;
    int*    counts_all = (int*)p;    p += (size_t)NTOT * 4;
    p = (char*)(((size_t)p + 255) & ~255ull);
    int*    scanG      = (int*)p;    p += (size_t)(SCANN + 64) * 4;  // 50177 + pad
    p = (char*)(((size_t)p + 255) & ~255ull);
    uint32* ell        = (uint32*)p; p += (size_t)16000000 * 4;     // 64 MB ELL
    uint32* mbf        = (uint32*)p; p += (size_t)NEDGE * 64 * 4;   // 12.8 MB
    uint32* poisbf     = (uint32*)p; p += (size_t)NPOI * 64 * 4;    // 25.6 MB
    uint32* xl[3];
    for (int l = 0; l < 3; l++) { xl[l] = (uint32*)p; p += (size_t)NPOI * 64 * 4; }
    // records (32 MB) alias xl[0..1] (51.2 MB): consumed by fillB before spmm writes xl.
    uint2* rec = (uint2*)xl[0];
    (void)ws_size; (void)out_size; (void)n_in; (void)in_sizes;

    // -------- ELL build: hist -> scan -> scatter-sort -> bucket fill --------
    histH_kernel<<<dim3(PB, 4), 1024, 0, stream>>>(
        rows_in[0], rows_in[1], rows_in[2], rows_in[3], scanG);
    scan_kernel<<<1, 256, 0, stream>>>(scanG);
    scatS_kernel<<<dim3(PB, 4), 1024, 0, stream>>>(
        rows_in[0], rows_in[1], rows_in[2], rows_in[3],
        cols_in[0], cols_in[1], cols_in[2], cols_in[3],
        vals_in[0], vals_in[1], vals_in[2], vals_in[3],
        scanG, rec);
    fillB_kernel<<<4 * NBKT, 512, 0, stream>>>(scanG, rec, counts_all, ell);

    // -------- attention weights + bf16 cast of pois --------
    softmax4_kernel<<<1, 64, 0, stream>>>(attn_di, attn_mv, wsoft);
    cast_bf16_kernel<<<ceil_div(NPOI * 64, 256), 256, 0, stream>>>(pois, poisbf, NPOI * 64);

    // -------- two branches, 3 layers each; epilogue per branch --------
    for (int br = 0; br < 2; br++) {
        int m1i = br ? 2 : 0;   // up  : tar   (50k rows, CAP 64)
        int m2i = br ? 3 : 1;   // pu  : src   (100k rows, CAP 48)
        const int* cn1 = counts_all + cnt_off[m1i];
        const int* cn2 = counts_all + cnt_off[m2i];
        const uint32* el1 = ell + ell_off[m1i];
        const uint32* el2 = ell + ell_off[m2i];
        const int n1 = 50000;  // NEDGE == NUSER
        const uint32* xcur = poisbf;
        for (int l = 1; l <= NL; l++) {
            spmm1_kernel<64><<<ceil_div(n1, 16), 256, 0, stream>>>(cn1, el1, xcur, mbf, n1);
            spmm2_kernel<48><<<ceil_div(NPOI, 16), 256, 0, stream>>>(
                cn2, el2, mbf, xcur, xl[l - 1], NPOI);
            xcur = xl[l - 1];
        }
        if (br == 0)
            epi1_kernel<<<ceil_div(NPOI * 64, 256), 256, 0, stream>>>(
                pois, xl[0], xl[1], xl[2], wsoft, out);
        else
            epi2_kernel<<<ceil_div(NPOI * 64, 256), 256, 0, stream>>>(
                xl[0], xl[1], xl[2], wsoft, out);
    }
}